// Round 3
// baseline (215.357 us; speedup 1.0000x reference)
//
#include <hip/hip_runtime.h>
#include <hip/hip_bf16.h>

// Problem constants
#define BB 4096
#define DD 512
#define HH 512
#define CC 8
#define N3H 1536
#define N4H 2048
#define NEG_BIG -1000000.0f

typedef __bf16 bf16x8 __attribute__((ext_vector_type(8)));
typedef float  f32x4  __attribute__((ext_vector_type(4)));
typedef _Float16 f16;

#define GL_LDS(gp, lp) \
    __builtin_amdgcn_global_load_lds( \
        (const __attribute__((address_space(1))) void*)(gp), \
        (__attribute__((address_space(3))) void*)(lp), 16, 0, 0)

// ---------------------------------------------------------------------------
// P0: convert c_input (32768 x 512) fp32 -> bf16, one wave per row, and fold
// the all-zero-row mask detection into the same pass.
// ---------------------------------------------------------------------------
__global__ __launch_bounds__(256) void k_prep_c(const float* __restrict__ c_in,
                                                __bf16* __restrict__ c_bf,
                                                float* __restrict__ maskmul) {
    const int wid  = threadIdx.x >> 6;
    const int lane = threadIdx.x & 63;
    const int row  = blockIdx.x * 4 + wid;   // 0..32767
    const float* p = c_in + (size_t)row * HH + lane * 8;
    const float4 v0 = *(const float4*)p;
    const float4 v1 = *(const float4*)(p + 4);
    bf16x8 o;
    o[0] = (__bf16)v0.x; o[1] = (__bf16)v0.y; o[2] = (__bf16)v0.z; o[3] = (__bf16)v0.w;
    o[4] = (__bf16)v1.x; o[5] = (__bf16)v1.y; o[6] = (__bf16)v1.z; o[7] = (__bf16)v1.w;
    *(bf16x8*)&c_bf[(size_t)row * HH + lane * 8] = o;
    const bool nz = (v0.x != 0.f) | (v0.y != 0.f) | (v0.z != 0.f) | (v0.w != 0.f) |
                    (v1.x != 0.f) | (v1.y != 0.f) | (v1.z != 0.f) | (v1.w != 0.f);
    const unsigned long long m = __ballot(nz);
    if (lane == 0) maskmul[row] = (m != 0ULL) ? 1.0f : NEG_BIG;
}

// ---------------------------------------------------------------------------
// P1: convert input (4096x512) and h0 (4096x512) to bf16, 8 elems/thread.
// ---------------------------------------------------------------------------
__global__ __launch_bounds__(256) void k_prep_ih(const float* __restrict__ input,
                                                 const float* __restrict__ h0,
                                                 __bf16* __restrict__ in_bf,
                                                 __bf16* __restrict__ h0_bf) {
    const size_t NIN = (size_t)BB * DD;
    size_t i = ((size_t)blockIdx.x * 256 + threadIdx.x) * 8;
    const float* src;
    __bf16* dst;
    if (i < NIN) { src = input + i; dst = in_bf + i; }
    else         { src = h0 + (i - NIN); dst = h0_bf + (i - NIN); }
    const float4 v0 = *(const float4*)src;
    const float4 v1 = *(const float4*)(src + 4);
    bf16x8 o;
    o[0] = (__bf16)v0.x; o[1] = (__bf16)v0.y; o[2] = (__bf16)v0.z; o[3] = (__bf16)v0.w;
    o[4] = (__bf16)v1.x; o[5] = (__bf16)v1.y; o[6] = (__bf16)v1.z; o[7] = (__bf16)v1.w;
    *(bf16x8*)dst = o;
}

// ---------------------------------------------------------------------------
// P2: transpose+convert all 4 weights into bf16 B^T (N x K, K=512) layout.
// ---------------------------------------------------------------------------
__global__ __launch_bounds__(256) void k_prep_w(
    const float* __restrict__ Wih, const float* __restrict__ Whh,
    const float* __restrict__ aWih, const float* __restrict__ aWhh,
    __bf16* __restrict__ WihT, __bf16* __restrict__ WhhT,
    __bf16* __restrict__ aWihT, __bf16* __restrict__ aWhhT) {
    __shared__ float tile[64][65];
    int tb = blockIdx.x;
    const float* W; __bf16* WT; int NN;
    if (tb < 192)      { W = Wih;  WT = WihT;  NN = N3H; }
    else if (tb < 384) { W = Whh;  WT = WhhT;  NN = N3H; tb -= 192; }
    else if (tb < 448) { W = aWih; WT = aWihT; NN = HH;  tb -= 384; }
    else               { W = aWhh; WT = aWhhT; NN = HH;  tb -= 448; }
    const int ntn = NN >> 6;
    const int kb = (tb / ntn) * 64, nb = (tb % ntn) * 64;
    const int t = threadIdx.x;
#pragma unroll
    for (int it = 0; it < 16; ++it) {
        const int idx = it * 256 + t;
        const int kk = idx >> 6, nn = idx & 63;
        tile[kk][nn] = W[(size_t)(kb + kk) * NN + nb + nn];
    }
    __syncthreads();
#pragma unroll
    for (int it = 0; it < 16; ++it) {
        const int idx = it * 256 + t;
        const int nn = idx >> 6, kk = idx & 63;
        WT[(size_t)(nb + nn) * DD + kb + kk] = (__bf16)tile[kk][nn];
    }
}

// ---------------------------------------------------------------------------
// MFMA core, 128x128 tile, BK=64 (as R2; verified conflict-free).
// ---------------------------------------------------------------------------
__device__ __forceinline__ void mfma_pass(
    const __bf16* __restrict__ A, const __bf16* __restrict__ B, int K,
    __bf16* As, __bf16* Bs, f32x4 (&acc)[4][4], int tid) {
    const int lane = tid & 63;
    const int wave = tid >> 6;
    const int ln = lane & 15, q = lane >> 4;
    const int wm = (wave & 1) * 64, wn = (wave >> 1) * 64;
    const int sm  = tid >> 3;
    const int scs = tid & 7;

    for (int k0 = 0; k0 < K; k0 += 64) {
        __syncthreads();
#pragma unroll
        for (int r = 0; r < 4; ++r) {
            const int m = sm + r * 32;
            const int c = scs ^ (m & 7);
            GL_LDS(A + (size_t)m * K + k0 + c * 8, As + m * 64 + scs * 8);
        }
#pragma unroll
        for (int r = 0; r < 4; ++r) {
            const int n = sm + r * 32;
            const int c = scs ^ (n & 7);
            GL_LDS(B + (size_t)n * K + k0 + c * 8, Bs + n * 64 + scs * 8);
        }
        __syncthreads();
#pragma unroll
        for (int kk = 0; kk < 64; kk += 32) {
            bf16x8 af[4], bfr[4];
#pragma unroll
            for (int ti = 0; ti < 4; ++ti) {
                const int m = wm + ti * 16 + ln;
                const int cs = ((kk >> 3) + q) ^ (m & 7);
                af[ti] = *(const bf16x8*)&As[m * 64 + cs * 8];
            }
#pragma unroll
            for (int tj = 0; tj < 4; ++tj) {
                const int n = wn + tj * 16 + ln;
                const int cs = ((kk >> 3) + q) ^ (n & 7);
                bfr[tj] = *(const bf16x8*)&Bs[n * 64 + cs * 8];
            }
#pragma unroll
            for (int ti = 0; ti < 4; ++ti)
#pragma unroll
                for (int tj = 0; tj < 4; ++tj)
                    acc[ti][tj] = __builtin_amdgcn_mfma_f32_16x16x32_bf16(
                        af[ti], bfr[tj], acc[ti][tj], 0, 0, 0);
        }
    }
}

// ---------------------------------------------------------------------------
// MFMA core variant: 128(M) x 256(N) tile, BK=64. Wave tile 64x128 (4x8).
// ---------------------------------------------------------------------------
__device__ __forceinline__ void mfma_pass_n256(
    const __bf16* __restrict__ A, const __bf16* __restrict__ B, int K,
    __bf16* As, __bf16* Bs, f32x4 (&acc)[4][8], int tid) {
    const int lane = tid & 63;
    const int wave = tid >> 6;
    const int ln = lane & 15, q = lane >> 4;
    const int wm = (wave & 1) * 64, wn = (wave >> 1) * 128;
    const int sm  = tid >> 3;
    const int scs = tid & 7;

    for (int k0 = 0; k0 < K; k0 += 64) {
        __syncthreads();
#pragma unroll
        for (int r = 0; r < 4; ++r) {
            const int m = sm + r * 32;
            const int c = scs ^ (m & 7);
            GL_LDS(A + (size_t)m * K + k0 + c * 8, As + m * 64 + scs * 8);
        }
#pragma unroll
        for (int r = 0; r < 8; ++r) {
            const int n = sm + r * 32;
            const int c = scs ^ (n & 7);
            GL_LDS(B + (size_t)n * K + k0 + c * 8, Bs + n * 64 + scs * 8);
        }
        __syncthreads();
#pragma unroll
        for (int kk = 0; kk < 64; kk += 32) {
            bf16x8 af[4], bfr[8];
#pragma unroll
            for (int ti = 0; ti < 4; ++ti) {
                const int m = wm + ti * 16 + ln;
                const int cs = ((kk >> 3) + q) ^ (m & 7);
                af[ti] = *(const bf16x8*)&As[m * 64 + cs * 8];
            }
#pragma unroll
            for (int tj = 0; tj < 8; ++tj) {
                const int n = wn + tj * 16 + ln;
                const int cs = ((kk >> 3) + q) ^ (n & 7);
                bfr[tj] = *(const bf16x8*)&Bs[n * 64 + cs * 8];
            }
#pragma unroll
            for (int ti = 0; ti < 4; ++ti)
#pragma unroll
                for (int tj = 0; tj < 8; ++tj)
                    acc[ti][tj] = __builtin_amdgcn_mfma_f32_16x16x32_bf16(
                        af[ti], bfr[tj], acc[ti][tj], 0, 0, 0);
        }
    }
}

// ---------------------------------------------------------------------------
// K1: gates (4096 x 2048) -> fp16.
//   cols [0,1536):  sig/sig/tanh( in@Wih + h0@Whh + bias )
//   cols [1536,2048): in@aWih + abias (raw)
// ---------------------------------------------------------------------------
__global__ __launch_bounds__(256, 2) void k_gates_mfma(
    const __bf16* __restrict__ in_bf, const __bf16* __restrict__ h0_bf,
    const __bf16* __restrict__ WihT, const __bf16* __restrict__ WhhT,
    const __bf16* __restrict__ aWihT, const float* __restrict__ bias,
    const float* __restrict__ abias, f16* __restrict__ gh) {
    __shared__ __bf16 As[128 * 64];
    __shared__ __bf16 Bs[128 * 64];
    f32x4 acc[4][4];
#pragma unroll
    for (int i = 0; i < 4; ++i)
#pragma unroll
        for (int j = 0; j < 4; ++j) acc[i][j] = (f32x4)0.f;

    const int n0 = blockIdx.x * 128;
    const int m0 = blockIdx.y * 128;
    const int tid = threadIdx.x;

    if (n0 < N3H) {
        mfma_pass(in_bf + (size_t)m0 * DD, WihT + (size_t)n0 * DD, DD, As, Bs, acc, tid);
        mfma_pass(h0_bf + (size_t)m0 * HH, WhhT + (size_t)n0 * DD, HH, As, Bs, acc, tid);
    } else {
        mfma_pass(in_bf + (size_t)m0 * DD, aWihT + (size_t)(n0 - N3H) * DD, DD, As, Bs, acc, tid);
    }

    const int lane = tid & 63, wave = tid >> 6;
    const int ln = lane & 15, q = lane >> 4;
    const int wm = (wave & 1) * 64, wn = (wave >> 1) * 64;
    const int region = n0 >> 9;  // 0,1: sigmoid; 2: tanh; 3: none

#pragma unroll
    for (int ti = 0; ti < 4; ++ti) {
#pragma unroll
        for (int tj = 0; tj < 4; ++tj) {
            const int col = n0 + wn + tj * 16 + ln;
            const float bv = (region < 3) ? bias[col] : abias[col - N3H];
#pragma unroll
            for (int reg = 0; reg < 4; ++reg) {
                const int row = m0 + wm + ti * 16 + q * 4 + reg;
                float x = acc[ti][tj][reg] + bv;
                if (region <= 1)      x = 1.f / (1.f + __expf(-x));
                else if (region == 2) x = tanhf(x);
                gh[(size_t)row * N4H + col] = (f16)x;
            }
        }
    }
}

// ---------------------------------------------------------------------------
// K2: alpha GEMM (32768 x 512 over K=512) with fully fused final epilogue.
// 128x256 block tile; merge values read as bf16 (L2/L3-warm from A-tiles).
// ---------------------------------------------------------------------------
__global__ __launch_bounds__(256, 2) void k_alpha_final(
    const __bf16* __restrict__ c_bf, const __bf16* __restrict__ aWhhT,
    const f16* __restrict__ gh, const float* __restrict__ maskmul,
    float* __restrict__ out) {
    __shared__ __bf16 As[128 * 64];
    __shared__ __bf16 Bs[256 * 64];
    __shared__ float maskLDS[128];
    f32x4 acc[4][8];
#pragma unroll
    for (int i = 0; i < 4; ++i)
#pragma unroll
        for (int j = 0; j < 8; ++j) acc[i][j] = (f32x4)0.f;

    const int n0 = blockIdx.x * 256;
    const int m0 = blockIdx.y * 128;
    const int tid = threadIdx.x;
    if (tid < 128) maskLDS[tid] = maskmul[m0 + tid];

    mfma_pass_n256(c_bf + (size_t)m0 * HH, aWhhT + (size_t)n0 * DD, HH, As, Bs, acc, tid);

    const int lane = tid & 63, wave = tid >> 6;
    const int ln = lane & 15, q = lane >> 4;
    const int wm = (wave & 1) * 64, wn = (wave >> 1) * 128;

#pragma unroll
    for (int ti = 0; ti < 4; ++ti) {
        const int rbase = wm + ti * 16 + q * 4;        // local row of quad
        const int bg = (m0 + rbase) >> 3;              // global b for this quad
        float mm[4];
#pragma unroll
        for (int reg = 0; reg < 4; ++reg) mm[reg] = maskLDS[rbase + reg];
#pragma unroll
        for (int tj = 0; tj < 8; ++tj) {
            const int h = n0 + wn + tj * 16 + ln;
            const float awi = (float)gh[(size_t)bg * N4H + N3H + h];
            float sden = 0.f, snum = 0.f;
#pragma unroll
            for (int reg = 0; reg < 4; ++reg) {
                const int rg = m0 + rbase + reg;
                const float s = 1.f / (1.f + __expf(-(acc[ti][tj][reg] + awi)));
                const float a = __expf(s * mm[reg]);   // masked -> exp(-huge) = 0
                const float cin = (float)c_bf[(size_t)rg * HH + h];
                sden += a;
                snum = fmaf(cin, a, snum);
            }
            sden += __shfl_xor(sden, 16);
            snum += __shfl_xor(snum, 16);
            if ((q & 1) == 0) {
                const float i_s = (float)gh[(size_t)bg * N4H + h];
                const float o_s = (float)gh[(size_t)bg * N4H + 512 + h];
                const float g_t = (float)gh[(size_t)bg * N4H + 1024 + h];
                const float e = __expf(i_s);
                const float c1 = fmaf(g_t, e, snum) / (e + sden);
                out[(size_t)bg * HH + h] = o_s * tanhf(c1);
                out[(size_t)BB * HH + (size_t)bg * HH + h] = c1;
            }
        }
    }
}

// ---------------------------------------------------------------------------
extern "C" void kernel_launch(void* const* d_in, const int* in_sizes, int n_in,
                              void* d_out, int out_size, void* d_ws, size_t ws_size,
                              hipStream_t stream) {
    const float* input = (const float*)d_in[0];
    const float* h0    = (const float*)d_in[1];
    // d_in[2] = c_0 (unused by reference)
    const float* c_in  = (const float*)d_in[3];
    const float* Wih   = (const float*)d_in[4];
    const float* Whh   = (const float*)d_in[5];
    const float* bias  = (const float*)d_in[6];
    const float* aWih  = (const float*)d_in[7];
    const float* aWhh  = (const float*)d_in[8];
    const float* abias = (const float*)d_in[9];
    float* out = (float*)d_out;

    // workspace layout (bytes)
    uint8_t* w = (uint8_t*)d_ws;
    __bf16* c_bf  = (__bf16*)w;                          // 32 MB
    __bf16* in_bf = (__bf16*)(w + (32u << 20));          //  4 MB
    __bf16* h0_bf = (__bf16*)(w + (36u << 20));          //  4 MB
    __bf16* WihT  = (__bf16*)(w + (40u << 20));          //  1.5 MB
    __bf16* WhhT  = (__bf16*)(w + (42u << 20));          //  1.5 MB
    __bf16* aWihT = (__bf16*)(w + (44u << 20));          //  0.5 MB
    __bf16* aWhhT = (__bf16*)(w + (45u << 20));          //  0.5 MB
    f16* gh       = (f16*)(w + (46u << 20));             // 16 MB
    float* maskmul = (float*)(w + (62u << 20));          // 128 KB

    k_prep_c<<<dim3(BB * CC / 4), dim3(256), 0, stream>>>(c_in, c_bf, maskmul);
    k_prep_ih<<<dim3(2 * BB * DD / (256 * 8)), dim3(256), 0, stream>>>(input, h0, in_bf, h0_bf);
    k_prep_w<<<dim3(512), dim3(256), 0, stream>>>(Wih, Whh, aWih, aWhh,
                                                  WihT, WhhT, aWihT, aWhhT);
    k_gates_mfma<<<dim3(N4H / 128, BB / 128), dim3(256), 0, stream>>>(
        in_bf, h0_bf, WihT, WhhT, aWihT, bias, abias, gh);
    k_alpha_final<<<dim3(HH / 256, BB * CC / 128), dim3(256), 0, stream>>>(
        c_bf, aWhhT, gh, maskmul, out);
}

// Round 4
// 203.783 us; speedup vs baseline: 1.0568x; 1.0568x over previous
//
#include <hip/hip_runtime.h>
#include <hip/hip_bf16.h>

// Problem constants
#define BB 4096
#define DD 512
#define HH 512
#define CC 8
#define N3H 1536
#define N4H 2048
#define NEG_BIG -1000000.0f

typedef __bf16 bf16x8 __attribute__((ext_vector_type(8)));
typedef float  f32x4  __attribute__((ext_vector_type(4)));
typedef _Float16 f16;
typedef _Float16 f16x8 __attribute__((ext_vector_type(8)));
typedef _Float16 f16x4 __attribute__((ext_vector_type(4)));

// a_lds leading stride (f16 elems): 132 -> 264B/row (66 dwords).
// Phase-1 ds_write_b16: q-groups step 4 rows = 264 dw = 8 banks (mod 32)
// -> {0,8,16,24}: disjoint octets, conflict-free. Row base is 8B-aligned.
#define ALDS_STRIDE 132

#define GL_LDS(gp, lp) \
    __builtin_amdgcn_global_load_lds( \
        (const __attribute__((address_space(1))) void*)(gp), \
        (__attribute__((address_space(3))) void*)(lp), 16, 0, 0)

// ---------------------------------------------------------------------------
// P: fused prep. blocks [0,8192): c conversion+mask; [8192,10240): in/h0
// conversion; [10240,10752): weight transpose.
// ---------------------------------------------------------------------------
__global__ __launch_bounds__(256) void k_prep_all(
    const float* __restrict__ c_in, __bf16* __restrict__ c_bf,
    float* __restrict__ maskmul,
    const float* __restrict__ input, const float* __restrict__ h0,
    __bf16* __restrict__ in_bf, __bf16* __restrict__ h0_bf,
    const float* __restrict__ Wih, const float* __restrict__ Whh,
    const float* __restrict__ aWih, const float* __restrict__ aWhh,
    __bf16* __restrict__ WihT, __bf16* __restrict__ WhhT,
    __bf16* __restrict__ aWihT, __bf16* __restrict__ aWhhT) {
    __shared__ float tile[64][65];
    const int blk = blockIdx.x;
    const int t = threadIdx.x;

    if (blk < 8192) {
        // ---- c_input -> bf16 + zero-row mask (one wave per row)
        const int wid  = t >> 6;
        const int lane = t & 63;
        const int row  = blk * 4 + wid;   // 0..32767
        const float* p = c_in + (size_t)row * HH + lane * 8;
        const float4 v0 = *(const float4*)p;
        const float4 v1 = *(const float4*)(p + 4);
        bf16x8 o;
        o[0] = (__bf16)v0.x; o[1] = (__bf16)v0.y; o[2] = (__bf16)v0.z; o[3] = (__bf16)v0.w;
        o[4] = (__bf16)v1.x; o[5] = (__bf16)v1.y; o[6] = (__bf16)v1.z; o[7] = (__bf16)v1.w;
        *(bf16x8*)&c_bf[(size_t)row * HH + lane * 8] = o;
        const bool nz = (v0.x != 0.f) | (v0.y != 0.f) | (v0.z != 0.f) | (v0.w != 0.f) |
                        (v1.x != 0.f) | (v1.y != 0.f) | (v1.z != 0.f) | (v1.w != 0.f);
        const unsigned long long m = __ballot(nz);
        if (lane == 0) maskmul[row] = (m != 0ULL) ? 1.0f : NEG_BIG;
    } else if (blk < 10240) {
        // ---- input / h0 -> bf16
        const size_t NIN = (size_t)BB * DD;
        size_t i = ((size_t)(blk - 8192) * 256 + t) * 8;
        const float* src;
        __bf16* dst;
        if (i < NIN) { src = input + i; dst = in_bf + i; }
        else         { src = h0 + (i - NIN); dst = h0_bf + (i - NIN); }
        const float4 v0 = *(const float4*)src;
        const float4 v1 = *(const float4*)(src + 4);
        bf16x8 o;
        o[0] = (__bf16)v0.x; o[1] = (__bf16)v0.y; o[2] = (__bf16)v0.z; o[3] = (__bf16)v0.w;
        o[4] = (__bf16)v1.x; o[5] = (__bf16)v1.y; o[6] = (__bf16)v1.z; o[7] = (__bf16)v1.w;
        *(bf16x8*)dst = o;
    } else {
        // ---- weight transpose (fp32 -> bf16 B^T layout)
        int tb = blk - 10240;
        const float* W; __bf16* WT; int NN;
        if (tb < 192)      { W = Wih;  WT = WihT;  NN = N3H; }
        else if (tb < 384) { W = Whh;  WT = WhhT;  NN = N3H; tb -= 192; }
        else if (tb < 448) { W = aWih; WT = aWihT; NN = HH;  tb -= 384; }
        else               { W = aWhh; WT = aWhhT; NN = HH;  tb -= 448; }
        const int ntn = NN >> 6;
        const int kb = (tb / ntn) * 64, nb = (tb % ntn) * 64;
#pragma unroll
        for (int it = 0; it < 16; ++it) {
            const int idx = it * 256 + t;
            const int kk = idx >> 6, nn = idx & 63;
            tile[kk][nn] = W[(size_t)(kb + kk) * NN + nb + nn];
        }
        __syncthreads();
#pragma unroll
        for (int it = 0; it < 16; ++it) {
            const int idx = it * 256 + t;
            const int nn = idx >> 6, kk = idx & 63;
            WT[(size_t)(nb + nn) * DD + kb + kk] = (__bf16)tile[kk][nn];
        }
    }
}

// ---------------------------------------------------------------------------
// MFMA core, 128x128 tile, BK=64 (verified conflict-free, XOR-swizzled LDS,
// global_load_lds width 16).
// ---------------------------------------------------------------------------
__device__ __forceinline__ void mfma_pass(
    const __bf16* __restrict__ A, const __bf16* __restrict__ B, int K,
    __bf16* As, __bf16* Bs, f32x4 (&acc)[4][4], int tid) {
    const int lane = tid & 63;
    const int wave = tid >> 6;
    const int ln = lane & 15, q = lane >> 4;
    const int wm = (wave & 1) * 64, wn = (wave >> 1) * 64;
    const int sm  = tid >> 3;
    const int scs = tid & 7;

    for (int k0 = 0; k0 < K; k0 += 64) {
        __syncthreads();
#pragma unroll
        for (int r = 0; r < 4; ++r) {
            const int m = sm + r * 32;
            const int c = scs ^ (m & 7);
            GL_LDS(A + (size_t)m * K + k0 + c * 8, As + m * 64 + scs * 8);
        }
#pragma unroll
        for (int r = 0; r < 4; ++r) {
            const int n = sm + r * 32;
            const int c = scs ^ (n & 7);
            GL_LDS(B + (size_t)n * K + k0 + c * 8, Bs + n * 64 + scs * 8);
        }
        __syncthreads();
#pragma unroll
        for (int kk = 0; kk < 64; kk += 32) {
            bf16x8 af[4], bfr[4];
#pragma unroll
            for (int ti = 0; ti < 4; ++ti) {
                const int m = wm + ti * 16 + ln;
                const int cs = ((kk >> 3) + q) ^ (m & 7);
                af[ti] = *(const bf16x8*)&As[m * 64 + cs * 8];
            }
#pragma unroll
            for (int tj = 0; tj < 4; ++tj) {
                const int n = wn + tj * 16 + ln;
                const int cs = ((kk >> 3) + q) ^ (n & 7);
                bfr[tj] = *(const bf16x8*)&Bs[n * 64 + cs * 8];
            }
#pragma unroll
            for (int ti = 0; ti < 4; ++ti)
#pragma unroll
                for (int tj = 0; tj < 4; ++tj)
                    acc[ti][tj] = __builtin_amdgcn_mfma_f32_16x16x32_bf16(
                        af[ti], bfr[tj], acc[ti][tj], 0, 0, 0);
        }
    }
}

// ---------------------------------------------------------------------------
// K1: gates (4096 x 2048) -> fp16.
//   cols [0,1536):  sig/sig/tanh( in@Wih + h0@Whh + bias )
//   cols [1536,2048): in@aWih + abias (raw)
// ---------------------------------------------------------------------------
__global__ __launch_bounds__(256, 2) void k_gates_mfma(
    const __bf16* __restrict__ in_bf, const __bf16* __restrict__ h0_bf,
    const __bf16* __restrict__ WihT, const __bf16* __restrict__ WhhT,
    const __bf16* __restrict__ aWihT, const float* __restrict__ bias,
    const float* __restrict__ abias, f16* __restrict__ gh) {
    __shared__ __bf16 As[128 * 64];
    __shared__ __bf16 Bs[128 * 64];
    f32x4 acc[4][4];
#pragma unroll
    for (int i = 0; i < 4; ++i)
#pragma unroll
        for (int j = 0; j < 4; ++j) acc[i][j] = (f32x4)0.f;

    const int n0 = blockIdx.x * 128;
    const int m0 = blockIdx.y * 128;
    const int tid = threadIdx.x;

    if (n0 < N3H) {
        mfma_pass(in_bf + (size_t)m0 * DD, WihT + (size_t)n0 * DD, DD, As, Bs, acc, tid);
        mfma_pass(h0_bf + (size_t)m0 * HH, WhhT + (size_t)n0 * DD, HH, As, Bs, acc, tid);
    } else {
        mfma_pass(in_bf + (size_t)m0 * DD, aWihT + (size_t)(n0 - N3H) * DD, DD, As, Bs, acc, tid);
    }

    const int lane = tid & 63, wave = tid >> 6;
    const int ln = lane & 15, q = lane >> 4;
    const int wm = (wave & 1) * 64, wn = (wave >> 1) * 64;
    const int region = n0 >> 9;  // 0,1: sigmoid; 2: tanh; 3: none

#pragma unroll
    for (int ti = 0; ti < 4; ++ti) {
#pragma unroll
        for (int tj = 0; tj < 4; ++tj) {
            const int col = n0 + wn + tj * 16 + ln;
            const float bv = (region < 3) ? bias[col] : abias[col - N3H];
#pragma unroll
            for (int reg = 0; reg < 4; ++reg) {
                const int row = m0 + wm + ti * 16 + q * 4 + reg;
                float x = acc[ti][tj][reg] + bv;
                if (region <= 1)      x = 1.f / (1.f + __expf(-x));
                else if (region == 2) x = tanhf(x);
                gh[(size_t)row * N4H + col] = (f16)x;
            }
        }
    }
}

// ---------------------------------------------------------------------------
// K2: alpha GEMM (32768 x 512, K=512) with fused final epilogue, v4.
// 128x128 tile, 4 blocks/CU. Phase-1 computes a=exp(sig(S+awi)*mm) into an
// LDS tile (unioned over the dead As/Bs). Phase-2 remaps threads to
// (b-group, 8h) for fully vectorized global loads/stores.
// ---------------------------------------------------------------------------
__global__ __launch_bounds__(256, 4) void k_alpha_final(
    const __bf16* __restrict__ c_bf, const __bf16* __restrict__ aWhhT,
    const f16* __restrict__ gh, const float* __restrict__ maskmul,
    float* __restrict__ out) {
    __shared__ __align__(16) char smem[128 * ALDS_STRIDE * 2];  // 33792 >= As+Bs
    __shared__ float maskLDS[128];
    __shared__ f16 awi_lds[16][128];
    __bf16* As = (__bf16*)smem;
    __bf16* Bs = (__bf16*)(smem + 16384);
    f16* a_lds = (f16*)smem;

    f32x4 acc[4][4];
#pragma unroll
    for (int i = 0; i < 4; ++i)
#pragma unroll
        for (int j = 0; j < 4; ++j) acc[i][j] = (f32x4)0.f;

    const int n0 = blockIdx.x * 128;
    const int m0 = blockIdx.y * 128;
    const int tid = threadIdx.x;
    const int bg0 = m0 >> 3;

    // cooperative preloads (coalesced); first barrier inside mfma_pass covers
    {
        const int bgl = tid >> 4, h8 = (tid & 15) * 8;
        *(f16x8*)&awi_lds[bgl][h8] =
            *(const f16x8*)&gh[(size_t)(bg0 + bgl) * N4H + N3H + n0 + h8];
        if (tid < 128) maskLDS[tid] = maskmul[m0 + tid];
    }

    mfma_pass(c_bf + (size_t)m0 * HH, aWhhT + (size_t)n0 * DD, HH, As, Bs, acc, tid);

    __syncthreads();  // all ds_reads of As/Bs done before a_lds overwrite

    const int lane = tid & 63, wave = tid >> 6;
    const int ln = lane & 15, q = lane >> 4;
    const int wm = (wave & 1) * 64, wn = (wave >> 1) * 64;

    // ---- phase 1: a values -> a_lds (conflict-free ds_write_b16)
#pragma unroll
    for (int ti = 0; ti < 4; ++ti) {
#pragma unroll
        for (int reg = 0; reg < 4; ++reg) {
            const int row = wm + ti * 16 + q * 4 + reg;
            const float mm = maskLDS[row];
            const f16* awr = awi_lds[row >> 3];
#pragma unroll
            for (int tj = 0; tj < 4; ++tj) {
                const int h = wn + tj * 16 + ln;
                const float s = 1.f / (1.f + __expf(-(acc[ti][tj][reg] + (float)awr[h])));
                a_lds[row * ALDS_STRIDE + h] = (f16)__expf(s * mm);
            }
        }
    }
    __syncthreads();

    // ---- phase 2: coalesced reduce + output
    const int bgl = tid >> 4;             // 0..15
    const int h8 = (tid & 15) * 8;        // 0..120
    const int hg = n0 + h8;
    const size_t grow = (size_t)(bg0 + bgl) * N4H;
    const f16x8 i8 = *(const f16x8*)&gh[grow + hg];
    const f16x8 o8 = *(const f16x8*)&gh[grow + 512 + hg];
    const f16x8 g8 = *(const f16x8*)&gh[grow + 1024 + hg];

    float num[8], den[8];
#pragma unroll
    for (int j = 0; j < 8; ++j) {
        const float e = __expf((float)i8[j]);
        den[j] = e;
        num[j] = (float)g8[j] * e;
    }
#pragma unroll
    for (int c = 0; c < CC; ++c) {
        const int arow = (bgl * 8 + c) * ALDS_STRIDE + h8;
        const f16x4 alo = *(const f16x4*)&a_lds[arow];
        const f16x4 ahi = *(const f16x4*)&a_lds[arow + 4];
        const bf16x8 cin8 = *(const bf16x8*)&c_bf[(size_t)(m0 + bgl * 8 + c) * HH + hg];
#pragma unroll
        for (int j = 0; j < 8; ++j) {
            const float a = (float)((j < 4) ? alo[j] : ahi[j - 4]);
            den[j] += a;
            num[j] = fmaf((float)cin8[j], a, num[j]);
        }
    }
    float h1[8], c1[8];
#pragma unroll
    for (int j = 0; j < 8; ++j) {
        c1[j] = num[j] / den[j];
        h1[j] = (float)o8[j] * tanhf(c1[j]);
    }
    const size_t obase = (size_t)(bg0 + bgl) * HH + hg;
    *(float4*)&out[obase]     = *(float4*)&h1[0];
    *(float4*)&out[obase + 4] = *(float4*)&h1[4];
    *(float4*)&out[(size_t)BB * HH + obase]     = *(float4*)&c1[0];
    *(float4*)&out[(size_t)BB * HH + obase + 4] = *(float4*)&c1[4];
}

// ---------------------------------------------------------------------------
extern "C" void kernel_launch(void* const* d_in, const int* in_sizes, int n_in,
                              void* d_out, int out_size, void* d_ws, size_t ws_size,
                              hipStream_t stream) {
    const float* input = (const float*)d_in[0];
    const float* h0    = (const float*)d_in[1];
    // d_in[2] = c_0 (unused by reference)
    const float* c_in  = (const float*)d_in[3];
    const float* Wih   = (const float*)d_in[4];
    const float* Whh   = (const float*)d_in[5];
    const float* bias  = (const float*)d_in[6];
    const float* aWih  = (const float*)d_in[7];
    const float* aWhh  = (const float*)d_in[8];
    const float* abias = (const float*)d_in[9];
    float* out = (float*)d_out;

    // workspace layout (bytes)
    uint8_t* w = (uint8_t*)d_ws;
    __bf16* c_bf  = (__bf16*)w;                          // 32 MB
    __bf16* in_bf = (__bf16*)(w + (32u << 20));          //  4 MB
    __bf16* h0_bf = (__bf16*)(w + (36u << 20));          //  4 MB
    __bf16* WihT  = (__bf16*)(w + (40u << 20));          //  1.5 MB
    __bf16* WhhT  = (__bf16*)(w + (42u << 20));          //  1.5 MB
    __bf16* aWihT = (__bf16*)(w + (44u << 20));          //  0.5 MB
    __bf16* aWhhT = (__bf16*)(w + (45u << 20));          //  0.5 MB
    f16* gh       = (f16*)(w + (46u << 20));             // 16 MB
    float* maskmul = (float*)(w + (62u << 20));          // 128 KB

    k_prep_all<<<dim3(10752), dim3(256), 0, stream>>>(
        c_in, c_bf, maskmul, input, h0, in_bf, h0_bf,
        Wih, Whh, aWih, aWhh, WihT, WhhT, aWihT, aWhhT);
    k_gates_mfma<<<dim3(N4H / 128, BB / 128), dim3(256), 0, stream>>>(
        in_bf, h0_bf, WihT, WhhT, aWihT, bias, abias, gh);
    k_alpha_final<<<dim3(HH / 128, BB * CC / 128), dim3(256), 0, stream>>>(
        c_bf, aWhhT, gh, maskmul, out);
}